// Round 3
// baseline (195.990 us; speedup 1.0000x reference)
//
#include <hip/hip_runtime.h>
#include <stdint.h>

#define DEV __device__ __forceinline__

typedef unsigned short u16;
typedef unsigned int u32;
typedef short bh8 __attribute__((ext_vector_type(8)));
typedef float f32x4 __attribute__((ext_vector_type(4)));

// ---------- bf16 helpers ----------
DEV float bf2f(u16 v){ return __uint_as_float(((u32)v)<<16); }
DEV u16 f2bf(float f){
    u32 x = __float_as_uint(f);
    x += 0x7fffu + ((x>>16)&1u);
    return (u16)(x>>16);
}
DEV void cvt8(int4 r, float* f){
    u32 a=(u32)r.x, b=(u32)r.y, c=(u32)r.z, d=(u32)r.w;
    f[0]=__uint_as_float(a<<16); f[1]=__uint_as_float(a&0xffff0000u);
    f[2]=__uint_as_float(b<<16); f[3]=__uint_as_float(b&0xffff0000u);
    f[4]=__uint_as_float(c<<16); f[5]=__uint_as_float(c&0xffff0000u);
    f[6]=__uint_as_float(d<<16); f[7]=__uint_as_float(d&0xffff0000u);
}
DEV int2 pk4(float a, float b, float c, float d){
    int2 r;
    r.x = (int)((u32)f2bf(a) | ((u32)f2bf(b)<<16));
    r.y = (int)((u32)f2bf(c) | ((u32)f2bf(d)<<16));
    return r;
}
DEV bh8 ld_frag(const u16* p){
    int4 v = *(const int4*)p;
    union{ int4 i; bh8 h; } u; u.i = v; return u.h;
}
#define MFMA __builtin_amdgcn_mfma_f32_16x16x32_bf16

// Problem constants: BSZ=1, S=256, C=128, H=4, D=32, F=64.
// I/O dtype: f32 (R7: bf16-read -> NaN; R8 first launch: f32 in/out passed). bf16 internal.

// Param block layout (elements, bf16) inside workspace (R6-verified):
#define P_LNW 0
#define P_LNB 128
#define P_QW  256
#define P_QB  16640
#define P_KW  16768
#define P_KB  33152
#define P_VW  33280
#define P_VB  49664
#define P_QFW 49792
#define P_QFB 50816
#define P_KFW 50848
#define P_KFB 51872
#define P_GW  51904
#define P_GB  68288
#define P_OW  68416
#define P_OB  84800
#define P_TOT 84928
// combined feature-map weights (appended):
#define P_CQW 84928    // [h][j][c] 4*32*128
#define P_CQB 101312   // [h][j]    4*32
#define P_CKW 101440
#define P_CKB 117824

#define NCONV 332      // blocks for the convert part (332*256 >= P_TOT)

// ---------------- params: f32 -> bf16 block + combined q/k feature weights ----------------
__global__ void prep_params(
    const float* p0, const float* p1, const float* p2, const float* p3,
    const float* p4, const float* p5, const float* p6, const float* p7,
    const float* p8, const float* p9, const float* p10, const float* p11,
    const float* p12, const float* p13, const float* p14, const float* p15,
    u16* __restrict__ dst){
    int b = blockIdx.x, tid = threadIdx.x;
    if(b < NCONV){
        int idx = b*256 + tid;
        if(idx >= P_TOT) return;
        const int offs[17] = {P_LNW,P_LNB,P_QW,P_QB,P_KW,P_KB,P_VW,P_VB,
                              P_QFW,P_QFB,P_KFW,P_KFB,P_GW,P_GB,P_OW,P_OB,P_TOT};
        const float* ptrs[16] = {p0,p1,p2,p3,p4,p5,p6,p7,p8,p9,p10,p11,p12,p13,p14,p15};
        int tsel = 0;
        #pragma unroll
        for(int i=1;i<16;++i) if(idx >= offs[i]) tsel = i;
        dst[idx] = f2bf(ptrs[tsel][idx - offs[tsel]]);
    } else if(b < NCONV + 128){
        // combined weights: Wc[h][j][c] = sum_d F[j][d] * W[h*32+d][c]
        int idx = (b - NCONV)*256 + tid;            // [0, 32768)
        int sel = idx >> 14;                        // 0=q, 1=k
        int rem = idx & 16383;
        int h = rem >> 12, j = (rem >> 7) & 31, c = rem & 127;
        const float* FWp = sel ? p10 : p8;
        const float* Wp  = sel ? p4  : p2;
        float s = 0.f;
        #pragma unroll
        for(int d=0; d<32; ++d)
            s += FWp[j*32+d] * Wp[(h*32+d)*128 + c];
        dst[(sel ? P_CKW : P_CQW) + h*4096 + j*128 + c] = f2bf(s);
    } else {
        // combined biases: bc[h][j] = sum_d F[j][d]*b[h*32+d] + fb[j]
        int t = tid;
        int sel = t >> 7, h = (t >> 5) & 3, j = t & 31;
        const float* FWp = sel ? p10 : p8;
        const float* FBp = sel ? p11 : p9;
        const float* Bp  = sel ? p5  : p3;
        float s = FBp[j];
        #pragma unroll
        for(int d=0; d<32; ++d)
            s += FWp[j*32+d] * Bp[h*32+d];
        dst[(sel ? P_CKB : P_CQB) + h*32 + j] = f2bf(s);
    }
}

// ---------------- LayerNorm: one wave per token (f32 in, bf16 out) ----------------
__global__ void ln_kernel(const float* __restrict__ zv, const u16* __restrict__ pb,
                          u16* __restrict__ zn){
    int t = blockIdx.x*4 + (threadIdx.x>>6);
    int lane = threadIdx.x & 63;
    float2 v = ((const float2*)zv)[(size_t)t*64 + lane];
    float x0 = v.x, x1 = v.y;
    float s = x0 + x1, s2 = x0*x0 + x1*x1;
    #pragma unroll
    for(int o=1;o<64;o<<=1){ s += __shfl_xor(s,o,64); s2 += __shfl_xor(s2,o,64); }
    float mean = s*(1.f/128.f);
    float var  = s2*(1.f/128.f) - mean*mean;
    float rs = rsqrtf(var + 1e-5f);
    int c0 = 2*lane;
    float w0 = bf2f(pb[P_LNW+c0]), w1 = bf2f(pb[P_LNW+c0+1]);
    float b0 = bf2f(pb[P_LNB+c0]), b1 = bf2f(pb[P_LNB+c0+1]);
    float o0 = (x0-mean)*rs*w0 + b0;
    float o1 = (x1-mean)*rs*w1 + b1;
    u32 po = (u32)f2bf(o0) | ((u32)f2bf(o1)<<16);
    *(u32*)(zn + (size_t)t*128 + c0) = po;
}

// ---------------- mega kernel: one block per (row, head) ----------------
// LDS: single u16[96][260] = 49920 B -> 3 blocks/CU needs total regs <= ~170.
// R2 post-mortem: (256,2) allocs >170 total regs -> only 2 blocks resident (occ 17%,
// same as R0). R1 proved 3 blocks fit (occ 24%) but 84-VGPR cap spilled (+57MB HBM).
// This version makes <=170 structurally feasible:
//   - phase 1 split into two sequential mt-halves (#pragma unroll 1): a[2][4]+acc[2][4]
//   - gate GEMM moved from phase 1 to phase 3 (same A-operand); gacc (32 regs) now
//     live only phase3->phase4 instead of whole kernel
//   - phase 3 split into two statically-unrolled halves (gacc indices compile-time)
// Layout (as R2):
//   kfT rows 0..63  : kf^T in f'-order (f' = 4*(j&15) + {ep_j, em_j, ep_{j+16}, em_{j+16}})
//   vT  rows 64..95 : v^T [d][n], masked
//   qf  (phases 3-4): [256][68] aliases offset 0 (34816 B)
//   kvT (phases 3-4): [33][68] at u16 offset 22712, overlaps dead vT tail (post-barrier)
// mask: per-thread 16-bit register mask (4 broadcast int4 loads), not LDS.
#define ST_N 260
#define ST_F 68
#define KVT_OFF 22712          // u16 offset; byte 45424, 16B aligned; ends at byte 49912
#define LDS_U16 (96*ST_N)      // 24960 u16 = 49920 B

__global__ __launch_bounds__(256,3)
void mega_kernel(const u16* __restrict__ zn, const int* __restrict__ mask,
                 const u16* __restrict__ pb, u16* __restrict__ attn){
    __shared__ __align__(16) u16 lds[LDS_U16];
    u16* kfT = lds;
    u16* vT  = lds + 64*ST_N;
    u16* qf  = lds;
    u16* kvT = lds + KVT_OFF;

    int g = blockIdx.x, row = g>>2, h = g&3;
    int tid = threadIdx.x, lane = tid & 63, wv = tid >> 6;
    int lm = lane & 15, quad = lane >> 4;

    // mask bits: bit (4*mt+r) = mask[row*256 + wv*64 + mt*16 + quad*4 + r]
    u32 mbits = 0;
    {
        const int4* mp = (const int4*)(mask + row*256 + wv*64 + quad*4);
        #pragma unroll
        for(int mt=0; mt<4; ++mt){
            int4 m = mp[mt*4];
            mbits |= ((u32)(m.x&1))<<(4*mt) | ((u32)(m.y&1))<<(4*mt+1)
                   | ((u32)(m.z&1))<<(4*mt+2) | ((u32)(m.w&1))<<(4*mt+3);
        }
    }

    bh8 onesf;
    { union{int4 i; bh8 h;} u2; u2.i.x=u2.i.y=u2.i.z=u2.i.w=0x3F803F80; onesf = u2.h; }

    const u16* Abase = zn + ((size_t)row*256 + wv*64 + lm)*128 + quad*8;

    // ---- phase 1 (two sequential halves): B = [ck0 ck1 | v0 v1] ----
    {
        float bk0 = bf2f(pb[P_CKB + h*32 + lm]);
        float bk1 = bf2f(pb[P_CKB + h*32 + 16 + lm]);
        float bv0 = bf2f(pb[P_VB + h*32 + lm]);
        float bv1 = bf2f(pb[P_VB + h*32 + 16 + lm]);
        #pragma unroll 1
        for(int hm=0; hm<2; ++hm){
            bh8 a2[2][4];
            const u16* Ab = Abase + (size_t)hm*32*128;
            #pragma unroll
            for(int m=0; m<2; ++m)
                #pragma unroll
                for(int ks=0; ks<4; ++ks)
                    a2[m][ks] = ld_frag(Ab + (size_t)m*16*128 + ks*32);
            f32x4 acc[2][4];
            #pragma unroll
            for(int m=0;m<2;++m)
                #pragma unroll
                for(int j=0;j<4;++j) acc[m][j] = (f32x4){0,0,0,0};
            #pragma unroll
            for(int ks=0; ks<4; ++ks){
                bh8 b[4];
                b[0] = ld_frag(pb + P_CKW + h*4096 + lm*128            + ks*32 + quad*8);
                b[1] = ld_frag(pb + P_CKW + h*4096 + (16+lm)*128       + ks*32 + quad*8);
                b[2] = ld_frag(pb + P_VW + (size_t)(h*32 + lm)*128     + ks*32 + quad*8);
                b[3] = ld_frag(pb + P_VW + (size_t)(h*32 + 16+lm)*128  + ks*32 + quad*8);
                #pragma unroll
                for(int m=0; m<2; ++m)
                    #pragma unroll
                    for(int j=0;j<4;++j)
                        acc[m][j] = MFMA(a2[m][ks], b[j], acc[m][j], 0,0,0);
            }
            #pragma unroll
            for(int m=0; m<2; ++m){
                int mt = hm*2 + m;
                int n0 = wv*64 + mt*16 + quad*4;
                float ep0[4], em0[4], ep1[4], em1[4], v0[4], v1[4];
                #pragma unroll
                for(int r=0; r<4; ++r){
                    float mk = (float)((mbits>>(4*mt+r))&1u);
                    float m0 = fminf(8.f, fmaxf(-8.f, acc[m][0][r] + bk0));
                    float m1 = fminf(8.f, fmaxf(-8.f, acc[m][1][r] + bk1));
                    ep0[r] = __expf( m0)*mk;  em0[r] = __expf(-m0)*mk;
                    ep1[r] = __expf( m1)*mk;  em1[r] = __expf(-m1)*mk;
                    v0[r] = (acc[m][2][r] + bv0)*mk;
                    v1[r] = (acc[m][3][r] + bv1)*mk;
                }
                *(int2*)(kfT + (size_t)(4*lm  )*ST_N + n0) = pk4(ep0[0],ep0[1],ep0[2],ep0[3]);
                *(int2*)(kfT + (size_t)(4*lm+1)*ST_N + n0) = pk4(em0[0],em0[1],em0[2],em0[3]);
                *(int2*)(kfT + (size_t)(4*lm+2)*ST_N + n0) = pk4(ep1[0],ep1[1],ep1[2],ep1[3]);
                *(int2*)(kfT + (size_t)(4*lm+3)*ST_N + n0) = pk4(em1[0],em1[1],em1[2],em1[3]);
                *(int2*)(vT  + (size_t)(lm   )*ST_N + n0) = pk4(v0[0],v0[1],v0[2],v0[3]);
                *(int2*)(vT  + (size_t)(16+lm)*ST_N + n0) = pk4(v1[0],v1[1],v1[2],v1[3]);
            }
        }
    }
    __syncthreads();
    // ---- phase 2: kv[f'][d] = sum_n kfT[f'][n]*vT[d][n]; ksum via ones-frag ----
    f32x4 kv0=(f32x4){0,0,0,0}, kv1=(f32x4){0,0,0,0}, ksm=(f32x4){0,0,0,0};
    #pragma unroll
    for(int ks=0; ks<8; ++ks){
        bh8 aa = ld_frag(kfT + (size_t)(wv*16+lm)*ST_N + ks*32 + quad*8);
        bh8 b0 = ld_frag(vT + (size_t)lm*ST_N      + ks*32 + quad*8);
        bh8 b1 = ld_frag(vT + (size_t)(16+lm)*ST_N + ks*32 + quad*8);
        kv0 = MFMA(aa, b0, kv0, 0,0,0);
        kv1 = MFMA(aa, b1, kv1, 0,0,0);
        ksm = MFMA(aa, onesf, ksm, 0,0,0);
    }
    __syncthreads();
    // kvT lives in the (now dead) vT tail; safe only after the barrier above.
    {
        int f0 = wv*16 + quad*4;
        *(int2*)(kvT + (size_t)(lm   )*ST_F + f0) = pk4(kv0[0],kv0[1],kv0[2],kv0[3]);
        *(int2*)(kvT + (size_t)(16+lm)*ST_F + f0) = pk4(kv1[0],kv1[1],kv1[2],kv1[3]);
        if(lm==0)
            *(int2*)(kvT + (size_t)32*ST_F + f0) = pk4(ksm[0],ksm[1],ksm[2],ksm[3]);
    }
    // ---- phase 3 (two halves): B = [cq0 cq1 | g0 g1]; qf + gate ----
    f32x4 gacc[4][2];
    {
        float bb0 = bf2f(pb[P_CQB + h*32 + lm]);
        float bb1 = bf2f(pb[P_CQB + h*32 + 16 + lm]);
        float bg0 = bf2f(pb[P_GB + h*32 + lm]);
        float bg1 = bf2f(pb[P_GB + h*32 + 16 + lm]);
        #pragma unroll
        for(int hm=0; hm<2; ++hm){
            bh8 a2[2][4];
            const u16* Ab = Abase + (size_t)hm*32*128;
            #pragma unroll
            for(int m=0; m<2; ++m)
                #pragma unroll
                for(int ks=0; ks<4; ++ks)
                    a2[m][ks] = ld_frag(Ab + (size_t)m*16*128 + ks*32);
            f32x4 acc[2][4];
            #pragma unroll
            for(int m=0;m<2;++m)
                #pragma unroll
                for(int j=0;j<4;++j) acc[m][j] = (f32x4){0,0,0,0};
            #pragma unroll
            for(int ks=0; ks<4; ++ks){
                bh8 b[4];
                b[0] = ld_frag(pb + P_CQW + h*4096 + lm*128            + ks*32 + quad*8);
                b[1] = ld_frag(pb + P_CQW + h*4096 + (16+lm)*128       + ks*32 + quad*8);
                b[2] = ld_frag(pb + P_GW + (size_t)(h*32 + lm)*128     + ks*32 + quad*8);
                b[3] = ld_frag(pb + P_GW + (size_t)(h*32 + 16+lm)*128  + ks*32 + quad*8);
                #pragma unroll
                for(int m=0; m<2; ++m)
                    #pragma unroll
                    for(int j=0;j<4;++j)
                        acc[m][j] = MFMA(a2[m][ks], b[j], acc[m][j], 0,0,0);
            }
            #pragma unroll
            for(int m=0; m<2; ++m){
                const int mt = hm*2 + m;
                #pragma unroll
                for(int r=0; r<4; ++r){
                    int n = wv*64 + mt*16 + quad*4 + r;
                    float m0 = fminf(8.f, fmaxf(-8.f, acc[m][0][r] + bb0));
                    float m1 = fminf(8.f, fmaxf(-8.f, acc[m][1][r] + bb1));
                    *(int2*)(qf + (size_t)n*ST_F + 4*lm) =
                        pk4(__expf(m0), __expf(-m0), __expf(m1), __expf(-m1));
                    gacc[mt][0][r] = 1.f/(1.f + __expf(-(acc[m][2][r] + bg0)));
                    gacc[mt][1][r] = 1.f/(1.f + __expf(-(acc[m][3][r] + bg1)));
                }
            }
        }
    }
    __syncthreads();
    // ---- phase 4: out = (qf·kvT^T)/den * gate ----
    {
        f32x4 acc[4][3];
        #pragma unroll
        for(int mt=0;mt<4;++mt)
            #pragma unroll
            for(int nt=0;nt<3;++nt) acc[mt][nt]=(f32x4){0,0,0,0};
        #pragma unroll
        for(int ks=0; ks<2; ++ks){
            bh8 b0 = ld_frag(kvT + (size_t)lm*ST_F      + ks*32 + quad*8);
            bh8 b1 = ld_frag(kvT + (size_t)(16+lm)*ST_F + ks*32 + quad*8);
            bh8 b2 = ld_frag(kvT + (size_t)32*ST_F      + ks*32 + quad*8); // ksum, broadcast
            #pragma unroll
            for(int mt=0; mt<4; ++mt){
                bh8 aa = ld_frag(qf + (size_t)(wv*64+mt*16+lm)*ST_F + ks*32 + quad*8);
                acc[mt][0] = MFMA(aa, b0, acc[mt][0], 0,0,0);
                acc[mt][1] = MFMA(aa, b1, acc[mt][1], 0,0,0);
                acc[mt][2] = MFMA(aa, b2, acc[mt][2], 0,0,0);
            }
        }
        #pragma unroll
        for(int mt=0; mt<4; ++mt)
            #pragma unroll
            for(int r=0; r<4; ++r){
                int n = wv*64 + mt*16 + quad*4 + r;
                float rcp = 1.f / fmaxf(acc[mt][2][r], 1e-6f);
                u16* op = attn + ((size_t)row*256 + n)*128 + h*32;
                op[lm]    = f2bf(acc[mt][0][r]*rcp*gacc[mt][0][r]);
                op[16+lm] = f2bf(acc[mt][1][r]*rcp*gacc[mt][1][r]);
            }
    }
}

// ---------------- MFMA o-proj: attn(bf16) -> out(f32), x mask ----------------
#define LDS_P 136
__global__ __launch_bounds__(256,2)
void oproj_kernel(const u16* __restrict__ attn, const u16* __restrict__ pb,
                  const int* __restrict__ mask, float* __restrict__ out){
    __shared__ u16 st[128*LDS_P];
    int tid = threadIdx.x;
    int lane = tid&63, wv = tid>>6;
    int mhalf = (wv>>1)*64, nhalf = (wv&1)*64;
    int lm = lane&15, quad = lane>>4;
    int m0 = blockIdx.x*128;

    f32x4 acc[4][4];
    #pragma unroll
    for(int mt=0;mt<4;++mt)
        #pragma unroll
        for(int nt=0;nt<4;++nt)
            acc[mt][nt] = (f32x4){0.f,0.f,0.f,0.f};

    const u16* Abase = attn + (size_t)(m0 + mhalf + lm)*128 + quad*8;
    const u16* W = pb + P_OW;
    #pragma unroll
    for(int ks=0; ks<4; ++ks){
        bh8 a[4], b[4];
        #pragma unroll
        for(int mt=0; mt<4; ++mt)
            a[mt] = ld_frag(Abase + (size_t)mt*16*128 + ks*32);
        #pragma unroll
        for(int nt=0; nt<4; ++nt)
            b[nt] = ld_frag(W + (size_t)(nhalf + nt*16 + lm)*128 + ks*32 + quad*8);
        #pragma unroll
        for(int mt=0; mt<4; ++mt)
            #pragma unroll
            for(int nt=0; nt<4; ++nt)
                acc[mt][nt] = MFMA(a[mt], b[nt], acc[mt][nt], 0, 0, 0);
    }
    float bv[4];
    #pragma unroll
    for(int nt=0; nt<4; ++nt) bv[nt] = bf2f(pb[P_OB + nhalf + nt*16 + lm]);
    #pragma unroll
    for(int mt=0; mt<4; ++mt){
        int mrow = m0 + mhalf + mt*16 + quad*4;
        float mk[4];
        #pragma unroll
        for(int r=0;r<4;++r) mk[r] = (float)mask[mrow+r];
        #pragma unroll
        for(int nt=0; nt<4; ++nt)
            #pragma unroll
            for(int r=0; r<4; ++r){
                float x = (acc[mt][nt][r] + bv[nt]) * mk[r];
                st[(mhalf + mt*16 + quad*4 + r)*LDS_P + nhalf + nt*16 + lm] = f2bf(x);
            }
    }
    __syncthreads();
    {
        int row = tid>>1, half = tid&1;
        const u16* src = st + row*LDS_P + half*64;
        float* dst = out + (size_t)(m0 + row)*128 + half*64;
        #pragma unroll
        for(int it=0; it<8; ++it){
            float f[8]; cvt8(((const int4*)src)[it], f);
            float4 lo; lo.x=f[0]; lo.y=f[1]; lo.z=f[2]; lo.w=f[3];
            float4 hi; hi.x=f[4]; hi.y=f[5]; hi.z=f[6]; hi.w=f[7];
            ((float4*)dst)[it*2  ] = lo;
            ((float4*)dst)[it*2+1] = hi;
        }
    }
}

// ---------------- launch ----------------
extern "C" void kernel_launch(void* const* d_in, const int* in_sizes, int n_in,
                              void* d_out, int out_size, void* d_ws, size_t ws_size,
                              hipStream_t stream){
    const float* z    = (const float*)d_in[0];
    const int*   mask = (const int*)d_in[1];

    char* ws = (char*)d_ws;
    const size_t MB = (size_t)1<<20;
    u16* zn   = (u16*)(ws + 0*MB);      // 16 MB [t][128] bf16
    u16* attn = (u16*)(ws + 16*MB);     // 16 MB [t][128] bf16
    u16* pb   = (u16*)(ws + 32*MB);     // ~231 KB bf16 param block (incl. combined weights)

    prep_params<<<NCONV+129,256,0,stream>>>(
        (const float*)d_in[2],  (const float*)d_in[3],  (const float*)d_in[4],  (const float*)d_in[5],
        (const float*)d_in[6],  (const float*)d_in[7],  (const float*)d_in[8],  (const float*)d_in[9],
        (const float*)d_in[10], (const float*)d_in[11], (const float*)d_in[12], (const float*)d_in[13],
        (const float*)d_in[14], (const float*)d_in[15], (const float*)d_in[16], (const float*)d_in[17],
        pb);
    ln_kernel<<<16384,256,0,stream>>>(z, pb, zn);
    mega_kernel<<<1024,256,0,stream>>>(zn, mask, pb, attn);
    oproj_kernel<<<512,256,0,stream>>>(attn, pb, mask, (float*)d_out);
}

// Round 5
// 189.604 us; speedup vs baseline: 1.0337x; 1.0337x over previous
//
#include <hip/hip_runtime.h>
#include <stdint.h>

#define DEV __device__ __forceinline__

typedef unsigned short u16;
typedef unsigned int u32;
typedef short bh8 __attribute__((ext_vector_type(8)));
typedef float f32x4 __attribute__((ext_vector_type(4)));

// ---------- bf16 helpers (software f2bf ONLY — R4: asm cvt_pk produced NaN; reverted) ----------
DEV float bf2f(u16 v){ return __uint_as_float(((u32)v)<<16); }
DEV u16 f2bf(float f){
    u32 x = __float_as_uint(f);
    x += 0x7fffu + ((x>>16)&1u);
    return (u16)(x>>16);
}
DEV void cvt8(int4 r, float* f){
    u32 a=(u32)r.x, b=(u32)r.y, c=(u32)r.z, d=(u32)r.w;
    f[0]=__uint_as_float(a<<16); f[1]=__uint_as_float(a&0xffff0000u);
    f[2]=__uint_as_float(b<<16); f[3]=__uint_as_float(b&0xffff0000u);
    f[4]=__uint_as_float(c<<16); f[5]=__uint_as_float(c&0xffff0000u);
    f[6]=__uint_as_float(d<<16); f[7]=__uint_as_float(d&0xffff0000u);
}
DEV int2 pk4(float a, float b, float c, float d){
    int2 r;
    r.x = (int)((u32)f2bf(a) | ((u32)f2bf(b)<<16));
    r.y = (int)((u32)f2bf(c) | ((u32)f2bf(d)<<16));
    return r;
}
DEV bh8 ld_frag(const u16* p){
    int4 v = *(const int4*)p;
    union{ int4 i; bh8 h; } u; u.i = v; return u.h;
}
#define MFMA __builtin_amdgcn_mfma_f32_16x16x32_bf16

// Problem constants: BSZ=1, S=256, C=128, H=4, D=32, F=64.
// I/O dtype: f32 in/out. bf16 internal.
//
// Session ledger:
//  R0: 4 kernels, mega 46.0us, total 183  <- fastest passing structure
//  R1: launch_bounds(256,3): VGPR cap 84 -> spills (+57MB WRITE), mega 62
//  R2: LDS 49920 + (256,2): VGPR 124 -> still 2 blocks/CU, mega 50
//  R3: phase-split + (256,3): occ 24.7% but zn re-read (+26MB FETCH), mega 58.5
//  R4: asm v_cvt_pk_bf16_f32 -> NaN (FAILED). Reverted; never hand-write cvt here.
//  => mega is latency-bound, not occupancy-bound. total-mega ~= 137us stable.
//  R5 (this): fuse LayerNorm INTO mega (delete ln kernel + zn buffer); 3 kernels.

// Param block layout (elements, bf16) inside workspace:
#define P_LNW 0
#define P_LNB 128
#define P_QW  256
#define P_QB  16640
#define P_KW  16768
#define P_KB  33152
#define P_VW  33280
#define P_VB  49664
#define P_QFW 49792
#define P_QFB 50816
#define P_KFW 50848
#define P_KFB 51872
#define P_GW  51904
#define P_GB  68288
#define P_OW  68416
#define P_OB  84800
#define P_TOT 84928
// combined feature-map weights (appended):
#define P_CQW 84928    // [h][j][c] 4*32*128
#define P_CQB 101312   // [h][j]    4*32
#define P_CKW 101440
#define P_CKB 117824

#define NCONV 332      // blocks for the convert part (332*256 >= P_TOT)

// ---------------- params: f32 -> bf16 block + combined q/k feature weights ----------------
__global__ void prep_params(
    const float* p0, const float* p1, const float* p2, const float* p3,
    const float* p4, const float* p5, const float* p6, const float* p7,
    const float* p8, const float* p9, const float* p10, const float* p11,
    const float* p12, const float* p13, const float* p14, const float* p15,
    u16* __restrict__ dst){
    int b = blockIdx.x, tid = threadIdx.x;
    if(b < NCONV){
        int idx = b*256 + tid;
        if(idx >= P_TOT) return;
        const int offs[17] = {P_LNW,P_LNB,P_QW,P_QB,P_KW,P_KB,P_VW,P_VB,
                              P_QFW,P_QFB,P_KFW,P_KFB,P_GW,P_GB,P_OW,P_OB,P_TOT};
        const float* ptrs[16] = {p0,p1,p2,p3,p4,p5,p6,p7,p8,p9,p10,p11,p12,p13,p14,p15};
        int tsel = 0;
        #pragma unroll
        for(int i=1;i<16;++i) if(idx >= offs[i]) tsel = i;
        dst[idx] = f2bf(ptrs[tsel][idx - offs[tsel]]);
    } else if(b < NCONV + 128){
        // combined weights: Wc[h][j][c] = sum_d F[j][d] * W[h*32+d][c]
        int idx = (b - NCONV)*256 + tid;            // [0, 32768)
        int sel = idx >> 14;                        // 0=q, 1=k
        int rem = idx & 16383;
        int h = rem >> 12, j = (rem >> 7) & 31, c = rem & 127;
        const float* FWp = sel ? p10 : p8;
        const float* Wp  = sel ? p4  : p2;
        float s = 0.f;
        #pragma unroll
        for(int d=0; d<32; ++d)
            s += FWp[j*32+d] * Wp[(h*32+d)*128 + c];
        dst[(sel ? P_CKW : P_CQW) + h*4096 + j*128 + c] = f2bf(s);
    } else {
        // combined biases: bc[h][j] = sum_d F[j][d]*b[h*32+d] + fb[j]
        int t = tid;
        int sel = t >> 7, h = (t >> 5) & 3, j = t & 31;
        const float* FWp = sel ? p10 : p8;
        const float* FBp = sel ? p11 : p9;
        const float* Bp  = sel ? p5  : p3;
        float s = FBp[j];
        #pragma unroll
        for(int d=0; d<32; ++d)
            s += FWp[j*32+d] * Bp[h*32+d];
        dst[(sel ? P_CKB : P_CQB) + h*32 + j] = f2bf(s);
    }
}

// ---------------- mega kernel: one block per (row, head), LN fused ----------------
// LDS (bytes): as R0 (proven 46us body):
//   mask_f [256 f32]      @ 0       (1024)
//   kfT    [64][264] u16  @ 1024    (33792)  kf^T [f][n], masked
//   vT     [32][264] u16  @ 34816   (16896)  v^T [d][n] masked
//   qf     [256][68] u16  @ 1024    (34816)  aliases kfT(+vT head); [n][f]
//   kvT    [33][68]  u16  @ 51712   (4488)   kv^T [d][f]; row 32 = ksum
// LN fusion: a-frags computed from z (f32) directly. Lane (lm,quad) holds token
// n = wv*64+mt*16+lm, channels quad*8+ks*32+[0..8). Per-token reduce = shfl_xor 16,32.
// Rounding path identical to old ln_kernel (f32 LN -> software f2bf) => same absmax.
// XCD swizzle: u=(g&7)*128+(g>>3) bijective on [0,1024); the 4 head-blocks of a row
// land on one XCD -> its 128KB z row is fetched into one L2, not four.
#define ST_N 264
#define ST_F 68
#define SM_KF   1024
#define SM_VT   34816
#define SM_QF   1024
#define SM_KVT  51712
#define SM_TOT  56200

__global__ __launch_bounds__(256,2)
void mega_kernel(const float* __restrict__ z, const int* __restrict__ mask,
                 const u16* __restrict__ pb, u16* __restrict__ attn){
    __shared__ __align__(16) char smem[SM_TOT];
    float* mask_f = (float*)smem;
    u16* kfT = (u16*)(smem + SM_KF);
    u16* vT  = (u16*)(smem + SM_VT);
    u16* qf  = (u16*)(smem + SM_QF);
    u16* kvT = (u16*)(smem + SM_KVT);

    int g = blockIdx.x;
    int u = (g & 7)*128 + (g >> 3);     // bijective XCD swizzle (1024 % 8 == 0)
    int row = u >> 2, h = u & 3;
    int tid = threadIdx.x, lane = tid & 63, wv = tid >> 6;
    int lm = lane & 15, quad = lane >> 4;

    mask_f[tid] = (float)mask[row*256 + tid];

    // ---- fused LayerNorm prologue: a[mt][ks] = bf16(LN(z)) fragments ----
    bh8 a[4][4];
    {
        bh8 wf[4], bfv[4];
        #pragma unroll
        for(int ks=0; ks<4; ++ks){
            wf[ks]  = ld_frag(pb + P_LNW + quad*8 + ks*32);
            bfv[ks] = ld_frag(pb + P_LNB + quad*8 + ks*32);
        }
        const float* zb = z + ((size_t)row*256 + wv*64 + lm)*128 + quad*8;
        #pragma unroll
        for(int mt=0; mt<4; ++mt){
            const float* zp = zb + (size_t)mt*16*128;
            float x[4][8];
            float s = 0.f, s2 = 0.f;
            #pragma unroll
            for(int ks=0; ks<4; ++ks){
                float4 u0 = *(const float4*)(zp + ks*32);
                float4 u1 = *(const float4*)(zp + ks*32 + 4);
                x[ks][0]=u0.x; x[ks][1]=u0.y; x[ks][2]=u0.z; x[ks][3]=u0.w;
                x[ks][4]=u1.x; x[ks][5]=u1.y; x[ks][6]=u1.z; x[ks][7]=u1.w;
                #pragma unroll
                for(int j=0;j<8;++j){ s += x[ks][j]; s2 += x[ks][j]*x[ks][j]; }
            }
            // token n's 128 channels live on lanes {lm, lm+16, lm+32, lm+48}
            s  += __shfl_xor(s, 16, 64);  s2 += __shfl_xor(s2, 16, 64);
            s  += __shfl_xor(s, 32, 64);  s2 += __shfl_xor(s2, 32, 64);
            float mean = s*(1.f/128.f);
            float var  = s2*(1.f/128.f) - mean*mean;
            float rs = rsqrtf(var + 1e-5f);
            #pragma unroll
            for(int ks=0; ks<4; ++ks){
                float y[8];
                #pragma unroll
                for(int j=0;j<8;++j)
                    y[j] = (x[ks][j]-mean)*rs*bf2f((u16)wf[ks][j]) + bf2f((u16)bfv[ks][j]);
                union{ int4 i; bh8 hh; } ua;
                ua.i.x = (int)((u32)f2bf(y[0]) | ((u32)f2bf(y[1])<<16));
                ua.i.y = (int)((u32)f2bf(y[2]) | ((u32)f2bf(y[3])<<16));
                ua.i.z = (int)((u32)f2bf(y[4]) | ((u32)f2bf(y[5])<<16));
                ua.i.w = (int)((u32)f2bf(y[6]) | ((u32)f2bf(y[7])<<16));
                a[mt][ks] = ua.hh;
            }
        }
    }
    bh8 onesf;
    { union{int4 i; bh8 hh;} u2; u2.i.x=u2.i.y=u2.i.z=u2.i.w=0x3F803F80; onesf = u2.hh; }

    __syncthreads();

    f32x4 gacc[4][2];
    // ---- phase 1 (merged): B = [ck0 ck1 | v0 v1 | g0 g1], shared A ----
    {
        f32x4 acc[4][6];
        #pragma unroll
        for(int mt=0;mt<4;++mt)
            #pragma unroll
            for(int j=0;j<6;++j) acc[mt][j] = (f32x4){0,0,0,0};
        #pragma unroll
        for(int ks=0; ks<4; ++ks){
            bh8 b[6];
            b[0] = ld_frag(pb + P_CKW + h*4096 + lm*128            + ks*32 + quad*8);
            b[1] = ld_frag(pb + P_CKW + h*4096 + (16+lm)*128       + ks*32 + quad*8);
            b[2] = ld_frag(pb + P_VW + (size_t)(h*32 + lm)*128     + ks*32 + quad*8);
            b[3] = ld_frag(pb + P_VW + (size_t)(h*32 + 16+lm)*128  + ks*32 + quad*8);
            b[4] = ld_frag(pb + P_GW + (size_t)(h*32 + lm)*128     + ks*32 + quad*8);
            b[5] = ld_frag(pb + P_GW + (size_t)(h*32 + 16+lm)*128  + ks*32 + quad*8);
            #pragma unroll
            for(int mt=0; mt<4; ++mt)
                #pragma unroll
                for(int j=0;j<6;++j)
                    acc[mt][j] = MFMA(a[mt][ks], b[j], acc[mt][j], 0,0,0);
        }
        float bk0 = bf2f(pb[P_CKB + h*32 + lm]);
        float bk1 = bf2f(pb[P_CKB + h*32 + 16 + lm]);
        float bv0 = bf2f(pb[P_VB + h*32 + lm]);
        float bv1 = bf2f(pb[P_VB + h*32 + 16 + lm]);
        float bg0 = bf2f(pb[P_GB + h*32 + lm]);
        float bg1 = bf2f(pb[P_GB + h*32 + 16 + lm]);
        #pragma unroll
        for(int mt=0; mt<4; ++mt){
            int n0 = wv*64 + mt*16 + quad*4;
            float ep0[4], em0[4], ep1[4], em1[4], v0[4], v1[4];
            #pragma unroll
            for(int r=0; r<4; ++r){
                float mk = mask_f[n0+r];
                float m0 = fminf(8.f, fmaxf(-8.f, acc[mt][0][r] + bk0));
                float m1 = fminf(8.f, fmaxf(-8.f, acc[mt][1][r] + bk1));
                ep0[r] = __expf( m0)*mk;  em0[r] = __expf(-m0)*mk;
                ep1[r] = __expf( m1)*mk;  em1[r] = __expf(-m1)*mk;
                v0[r] = (acc[mt][2][r] + bv0)*mk;
                v1[r] = (acc[mt][3][r] + bv1)*mk;
                gacc[mt][0][r] = 1.f/(1.f + __expf(-(acc[mt][4][r] + bg0)));
                gacc[mt][1][r] = 1.f/(1.f + __expf(-(acc[mt][5][r] + bg1)));
            }
            *(int2*)(kfT + (size_t)(lm   )*ST_N + n0) = pk4(ep0[0],ep0[1],ep0[2],ep0[3]);
            *(int2*)(kfT + (size_t)(lm+32)*ST_N + n0) = pk4(em0[0],em0[1],em0[2],em0[3]);
            *(int2*)(kfT + (size_t)(lm+16)*ST_N + n0) = pk4(ep1[0],ep1[1],ep1[2],ep1[3]);
            *(int2*)(kfT + (size_t)(lm+48)*ST_N + n0) = pk4(em1[0],em1[1],em1[2],em1[3]);
            *(int2*)(vT  + (size_t)(lm   )*ST_N + n0) = pk4(v0[0],v0[1],v0[2],v0[3]);
            *(int2*)(vT  + (size_t)(16+lm)*ST_N + n0) = pk4(v1[0],v1[1],v1[2],v1[3]);
        }
    }
    __syncthreads();
    // ---- phase 2: kvT[d][f] = sum_n kfT[f][n]*vT[d][n]; ksum via ones-frag ----
    {
        f32x4 acc0=(f32x4){0,0,0,0}, acc1=(f32x4){0,0,0,0}, acc2=(f32x4){0,0,0,0};
        #pragma unroll
        for(int ks=0; ks<8; ++ks){
            bh8 aa = ld_frag(kfT + (size_t)(wv*16+lm)*ST_N + ks*32 + quad*8);
            bh8 b0 = ld_frag(vT + (size_t)lm*ST_N      + ks*32 + quad*8);
            bh8 b1 = ld_frag(vT + (size_t)(16+lm)*ST_N + ks*32 + quad*8);
            acc0 = MFMA(aa, b0, acc0, 0,0,0);
            acc1 = MFMA(aa, b1, acc1, 0,0,0);
            acc2 = MFMA(aa, onesf, acc2, 0,0,0);
        }
        int f0 = wv*16 + quad*4;
        *(int2*)(kvT + (size_t)(lm   )*ST_F + f0) = pk4(acc0[0],acc0[1],acc0[2],acc0[3]);
        *(int2*)(kvT + (size_t)(16+lm)*ST_F + f0) = pk4(acc1[0],acc1[1],acc1[2],acc1[3]);
        if(lm==0)
            *(int2*)(kvT + (size_t)32*ST_F + f0) = pk4(acc2[0],acc2[1],acc2[2],acc2[3]);
    }
    __syncthreads();
    // ---- phase 3: qf[n][f] = featmap(zn·Wc_q^T + bc_q)  (aliases kfT/vT) ----
    {
        f32x4 acc[4][2];
        #pragma unroll
        for(int mt=0;mt<4;++mt){ acc[mt][0]=(f32x4){0,0,0,0}; acc[mt][1]=(f32x4){0,0,0,0}; }
        #pragma unroll
        for(int ks=0; ks<4; ++ks){
            bh8 b0 = ld_frag(pb + P_CQW + h*4096 + lm*128      + ks*32 + quad*8);
            bh8 b1 = ld_frag(pb + P_CQW + h*4096 + (16+lm)*128 + ks*32 + quad*8);
            #pragma unroll
            for(int mt=0; mt<4; ++mt){
                acc[mt][0] = MFMA(a[mt][ks], b0, acc[mt][0], 0,0,0);
                acc[mt][1] = MFMA(a[mt][ks], b1, acc[mt][1], 0,0,0);
            }
        }
        float bb0 = bf2f(pb[P_CQB + h*32 + lm]);
        float bb1 = bf2f(pb[P_CQB + h*32 + 16 + lm]);
        #pragma unroll
        for(int mt=0; mt<4; ++mt)
            #pragma unroll
            for(int r=0; r<4; ++r){
                int n = wv*64 + mt*16 + quad*4 + r;
                float m0 = fminf(8.f, fmaxf(-8.f, acc[mt][0][r] + bb0));
                float m1 = fminf(8.f, fmaxf(-8.f, acc[mt][1][r] + bb1));
                qf[n*ST_F + lm     ] = f2bf(__expf( m0));
                qf[n*ST_F + lm + 32] = f2bf(__expf(-m0));
                qf[n*ST_F + lm + 16] = f2bf(__expf( m1));
                qf[n*ST_F + lm + 48] = f2bf(__expf(-m1));
            }
    }
    __syncthreads();
    // ---- phase 4: out = (qf·kvT^T)/den * gate ----
    {
        f32x4 acc[4][3];
        #pragma unroll
        for(int mt=0;mt<4;++mt)
            #pragma unroll
            for(int nt=0;nt<3;++nt) acc[mt][nt]=(f32x4){0,0,0,0};
        #pragma unroll
        for(int ks=0; ks<2; ++ks){
            bh8 b0 = ld_frag(kvT + (size_t)lm*ST_F      + ks*32 + quad*8);
            bh8 b1 = ld_frag(kvT + (size_t)(16+lm)*ST_F + ks*32 + quad*8);
            bh8 b2 = ld_frag(kvT + (size_t)32*ST_F      + ks*32 + quad*8); // ksum, broadcast
            #pragma unroll
            for(int mt=0; mt<4; ++mt){
                bh8 aa = ld_frag(qf + (size_t)(wv*64+mt*16+lm)*ST_F + ks*32 + quad*8);
                acc[mt][0] = MFMA(aa, b0, acc[mt][0], 0,0,0);
                acc[mt][1] = MFMA(aa, b1, acc[mt][1], 0,0,0);
                acc[mt][2] = MFMA(aa, b2, acc[mt][2], 0,0,0);
            }
        }
        #pragma unroll
        for(int mt=0; mt<4; ++mt)
            #pragma unroll
            for(int r=0; r<4; ++r){
                int n = wv*64 + mt*16 + quad*4 + r;
                float rcp = 1.f / fmaxf(acc[mt][2][r], 1e-6f);
                u16* op = attn + ((size_t)row*256 + n)*128 + h*32;
                op[lm]    = f2bf(acc[mt][0][r]*rcp*gacc[mt][0][r]);
                op[16+lm] = f2bf(acc[mt][1][r]*rcp*gacc[mt][1][r]);
            }
    }
}

// ---------------- MFMA o-proj: attn(bf16) -> out(f32), x mask ----------------
#define LDS_P 136
__global__ __launch_bounds__(256,2)
void oproj_kernel(const u16* __restrict__ attn, const u16* __restrict__ pb,
                  const int* __restrict__ mask, float* __restrict__ out){
    __shared__ u16 st[128*LDS_P];
    int tid = threadIdx.x;
    int lane = tid&63, wv = tid>>6;
    int mhalf = (wv>>1)*64, nhalf = (wv&1)*64;
    int lm = lane&15, quad = lane>>4;
    int m0 = blockIdx.x*128;

    f32x4 acc[4][4];
    #pragma unroll
    for(int mt=0;mt<4;++mt)
        #pragma unroll
        for(int nt=0;nt<4;++nt)
            acc[mt][nt] = (f32x4){0.f,0.f,0.f,0.f};

    const u16* Abase = attn + (size_t)(m0 + mhalf + lm)*128 + quad*8;
    const u16* W = pb + P_OW;
    #pragma unroll
    for(int ks=0; ks<4; ++ks){
        bh8 a[4], b[4];
        #pragma unroll
        for(int mt=0; mt<4; ++mt)
            a[mt] = ld_frag(Abase + (size_t)mt*16*128 + ks*32);
        #pragma unroll
        for(int nt=0; nt<4; ++nt)
            b[nt] = ld_frag(W + (size_t)(nhalf + nt*16 + lm)*128 + ks*32 + quad*8);
        #pragma unroll
        for(int mt=0; mt<4; ++mt)
            #pragma unroll
            for(int nt=0; nt<4; ++nt)
                acc[mt][nt] = MFMA(a[mt], b[nt], acc[mt][nt], 0, 0, 0);
    }
    float bv[4];
    #pragma unroll
    for(int nt=0; nt<4; ++nt) bv[nt] = bf2f(pb[P_OB + nhalf + nt*16 + lm]);
    #pragma unroll
    for(int mt=0; mt<4; ++mt){
        int mrow = m0 + mhalf + mt*16 + quad*4;
        float mk[4];
        #pragma unroll
        for(int r=0;r<4;++r) mk[r] = (float)mask[mrow+r];
        #pragma unroll
        for(int nt=0; nt<4; ++nt)
            #pragma unroll
            for(int r=0; r<4; ++r){
                float x = (acc[mt][nt][r] + bv[nt]) * mk[r];
                st[(mhalf + mt*16 + quad*4 + r)*LDS_P + nhalf + nt*16 + lm] = f2bf(x);
            }
    }
    __syncthreads();
    {
        int row = tid>>1, half = tid&1;
        const u16* src = st + row*LDS_P + half*64;
        float* dst = out + (size_t)(m0 + row)*128 + half*64;
        #pragma unroll
        for(int it=0; it<8; ++it){
            float f[8]; cvt8(((const int4*)src)[it], f);
            float4 lo; lo.x=f[0]; lo.y=f[1]; lo.z=f[2]; lo.w=f[3];
            float4 hi; hi.x=f[4]; hi.y=f[5]; hi.z=f[6]; hi.w=f[7];
            ((float4*)dst)[it*2  ] = lo;
            ((float4*)dst)[it*2+1] = hi;
        }
    }
}

// ---------------- launch: 3 kernels (ln fused into mega) ----------------
extern "C" void kernel_launch(void* const* d_in, const int* in_sizes, int n_in,
                              void* d_out, int out_size, void* d_ws, size_t ws_size,
                              hipStream_t stream){
    const float* z    = (const float*)d_in[0];
    const int*   mask = (const int*)d_in[1];

    char* ws = (char*)d_ws;
    const size_t MB = (size_t)1<<20;
    u16* attn = (u16*)(ws + 16*MB);     // 16 MB [t][128] bf16
    u16* pb   = (u16*)(ws + 32*MB);     // ~231 KB bf16 param block (incl. combined weights)

    prep_params<<<NCONV+129,256,0,stream>>>(
        (const float*)d_in[2],  (const float*)d_in[3],  (const float*)d_in[4],  (const float*)d_in[5],
        (const float*)d_in[6],  (const float*)d_in[7],  (const float*)d_in[8],  (const float*)d_in[9],
        (const float*)d_in[10], (const float*)d_in[11], (const float*)d_in[12], (const float*)d_in[13],
        (const float*)d_in[14], (const float*)d_in[15], (const float*)d_in[16], (const float*)d_in[17],
        pb);
    mega_kernel<<<1024,256,0,stream>>>(z, mask, pb, attn);
    oproj_kernel<<<512,256,0,stream>>>(attn, pb, mask, (float*)d_out);
}

// Round 6
// 184.792 us; speedup vs baseline: 1.0606x; 1.0260x over previous
//
#include <hip/hip_runtime.h>
#include <stdint.h>

#define DEV __device__ __forceinline__

typedef unsigned short u16;
typedef unsigned int u32;
typedef short bh8 __attribute__((ext_vector_type(8)));
typedef float f32x4 __attribute__((ext_vector_type(4)));

// ---------- bf16 helpers (software f2bf ONLY — R4: asm cvt_pk produced NaN; reverted) ----------
DEV float bf2f(u16 v){ return __uint_as_float(((u32)v)<<16); }
DEV u16 f2bf(float f){
    u32 x = __float_as_uint(f);
    x += 0x7fffu + ((x>>16)&1u);
    return (u16)(x>>16);
}
DEV void cvt8(int4 r, float* f){
    u32 a=(u32)r.x, b=(u32)r.y, c=(u32)r.z, d=(u32)r.w;
    f[0]=__uint_as_float(a<<16); f[1]=__uint_as_float(a&0xffff0000u);
    f[2]=__uint_as_float(b<<16); f[3]=__uint_as_float(b&0xffff0000u);
    f[4]=__uint_as_float(c<<16); f[5]=__uint_as_float(c&0xffff0000u);
    f[6]=__uint_as_float(d<<16); f[7]=__uint_as_float(d&0xffff0000u);
}
DEV int2 pk4(float a, float b, float c, float d){
    int2 r;
    r.x = (int)((u32)f2bf(a) | ((u32)f2bf(b)<<16));
    r.y = (int)((u32)f2bf(c) | ((u32)f2bf(d)<<16));
    return r;
}
DEV bh8 ld_frag(const u16* p){
    int4 v = *(const int4*)p;
    union{ int4 i; bh8 h; } u; u.i = v; return u.h;
}
#define MFMA __builtin_amdgcn_mfma_f32_16x16x32_bf16

// Problem constants: BSZ=1, S=256, C=128, H=4, D=32, F=64.
// I/O dtype: f32 in/out. bf16 internal.
//
// Session ledger:
//  R0: 4 kernels, mega 46.0us, total 183  <- fastest passing structure
//  R1: launch_bounds(256,3): VGPR cap 84 -> spills (+57MB WRITE), mega 62
//  R2: LDS 49920 + (256,2): VGPR 124 -> still 2 blocks/CU, mega 50
//  R3: phase-split + (256,3): occ 24.7% but zn re-read (+26MB FETCH), mega 58.5
//  R4: asm v_cvt_pk_bf16_f32 -> NaN (FAILED). Never hand-write cvt here.
//  R5: LN fused into mega: non-mega 137->90us (ln launch was ~47us!) BUT prologue
//      x[4][8] interleaved across mt -> spills (+26MB WRITE), mega 99us. total 189.6.
//  R6 (this): same fusion, mt bodies serialized via sched_barrier(0) -> no spills.
//      Decision metric: WRITE_SIZE must return to ~16.4MB.

// Param block layout (elements, bf16) inside workspace:
#define P_LNW 0
#define P_LNB 128
#define P_QW  256
#define P_QB  16640
#define P_KW  16768
#define P_KB  33152
#define P_VW  33280
#define P_VB  49664
#define P_QFW 49792
#define P_QFB 50816
#define P_KFW 50848
#define P_KFB 51872
#define P_GW  51904
#define P_GB  68288
#define P_OW  68416
#define P_OB  84800
#define P_TOT 84928
// combined feature-map weights (appended):
#define P_CQW 84928    // [h][j][c] 4*32*128
#define P_CQB 101312   // [h][j]    4*32
#define P_CKW 101440
#define P_CKB 117824

#define NCONV 332      // blocks for the convert part (332*256 >= P_TOT)

// ---------------- params: f32 -> bf16 block + combined q/k feature weights ----------------
__global__ void prep_params(
    const float* p0, const float* p1, const float* p2, const float* p3,
    const float* p4, const float* p5, const float* p6, const float* p7,
    const float* p8, const float* p9, const float* p10, const float* p11,
    const float* p12, const float* p13, const float* p14, const float* p15,
    u16* __restrict__ dst){
    int b = blockIdx.x, tid = threadIdx.x;
    if(b < NCONV){
        int idx = b*256 + tid;
        if(idx >= P_TOT) return;
        const int offs[17] = {P_LNW,P_LNB,P_QW,P_QB,P_KW,P_KB,P_VW,P_VB,
                              P_QFW,P_QFB,P_KFW,P_KFB,P_GW,P_GB,P_OW,P_OB,P_TOT};
        const float* ptrs[16] = {p0,p1,p2,p3,p4,p5,p6,p7,p8,p9,p10,p11,p12,p13,p14,p15};
        int tsel = 0;
        #pragma unroll
        for(int i=1;i<16;++i) if(idx >= offs[i]) tsel = i;
        dst[idx] = f2bf(ptrs[tsel][idx - offs[tsel]]);
    } else if(b < NCONV + 128){
        // combined weights: Wc[h][j][c] = sum_d F[j][d] * W[h*32+d][c]
        int idx = (b - NCONV)*256 + tid;            // [0, 32768)
        int sel = idx >> 14;                        // 0=q, 1=k
        int rem = idx & 16383;
        int h = rem >> 12, j = (rem >> 7) & 31, c = rem & 127;
        const float* FWp = sel ? p10 : p8;
        const float* Wp  = sel ? p4  : p2;
        float s = 0.f;
        #pragma unroll
        for(int d=0; d<32; ++d)
            s += FWp[j*32+d] * Wp[(h*32+d)*128 + c];
        dst[(sel ? P_CKW : P_CQW) + h*4096 + j*128 + c] = f2bf(s);
    } else {
        // combined biases: bc[h][j] = sum_d F[j][d]*b[h*32+d] + fb[j]
        int t = tid;
        int sel = t >> 7, h = (t >> 5) & 3, j = t & 31;
        const float* FWp = sel ? p10 : p8;
        const float* FBp = sel ? p11 : p9;
        const float* Bp  = sel ? p5  : p3;
        float s = FBp[j];
        #pragma unroll
        for(int d=0; d<32; ++d)
            s += FWp[j*32+d] * Bp[h*32+d];
        dst[(sel ? P_CKB : P_CQB) + h*32 + j] = f2bf(s);
    }
}

// ---------------- mega kernel: one block per (row, head), LN fused ----------------
// LDS layout as R0 (proven 46us body):
//   mask_f [256 f32]      @ 0       (1024)
//   kfT    [64][264] u16  @ 1024    (33792)  kf^T [f][n], masked
//   vT     [32][264] u16  @ 34816   (16896)  v^T [d][n] masked
//   qf     [256][68] u16  @ 1024    (34816)  aliases kfT(+vT head); [n][f]
//   kvT    [33][68]  u16  @ 51712   (4488)   kv^T [d][f]; row 32 = ksum
// LN fusion: a-frags from z (f32) directly; token n on lanes {lm,lm+16,lm+32,lm+48},
// reduce = shfl_xor 16,32. Same f32 math + software f2bf as old ln_kernel.
// R6 fix: sched_barrier(0) after each mt body -> mt iterations execute serially,
// capping liveness at ~one mt's x[4][8] (R5 interleaved all 4 -> spilled).
// XCD swizzle: u=(g&7)*128+(g>>3) bijective; 4 head-blocks of a row share one XCD L2
// (R5 measured: FETCH 33.6 -> 26.3 MB).
#define ST_N 264
#define ST_F 68
#define SM_KF   1024
#define SM_VT   34816
#define SM_QF   1024
#define SM_KVT  51712
#define SM_TOT  56200

__global__ __launch_bounds__(256,2)
void mega_kernel(const float* __restrict__ z, const int* __restrict__ mask,
                 const u16* __restrict__ pb, u16* __restrict__ attn){
    __shared__ __align__(16) char smem[SM_TOT];
    float* mask_f = (float*)smem;
    u16* kfT = (u16*)(smem + SM_KF);
    u16* vT  = (u16*)(smem + SM_VT);
    u16* qf  = (u16*)(smem + SM_QF);
    u16* kvT = (u16*)(smem + SM_KVT);

    int g = blockIdx.x;
    int u = (g & 7)*128 + (g >> 3);     // bijective XCD swizzle (1024 % 8 == 0)
    int row = u >> 2, h = u & 3;
    int tid = threadIdx.x, lane = tid & 63, wv = tid >> 6;
    int lm = lane & 15, quad = lane >> 4;

    mask_f[tid] = (float)mask[row*256 + tid];

    // ---- fused LayerNorm prologue: a[mt][ks] = bf16(LN(z)) fragments ----
    bh8 a[4][4];
    {
        bh8 wf[4], bfv[4];
        #pragma unroll
        for(int ks=0; ks<4; ++ks){
            wf[ks]  = ld_frag(pb + P_LNW + quad*8 + ks*32);
            bfv[ks] = ld_frag(pb + P_LNB + quad*8 + ks*32);
        }
        const float* zb = z + ((size_t)row*256 + wv*64 + lm)*128 + quad*8;
        #pragma unroll
        for(int mt=0; mt<4; ++mt){
            const float* zp = zb + (size_t)mt*16*128;
            float x[4][8];
            float s = 0.f, s2 = 0.f;
            #pragma unroll
            for(int ks=0; ks<4; ++ks){
                float4 u0 = *(const float4*)(zp + ks*32);
                float4 u1 = *(const float4*)(zp + ks*32 + 4);
                x[ks][0]=u0.x; x[ks][1]=u0.y; x[ks][2]=u0.z; x[ks][3]=u0.w;
                x[ks][4]=u1.x; x[ks][5]=u1.y; x[ks][6]=u1.z; x[ks][7]=u1.w;
                #pragma unroll
                for(int j=0;j<8;++j){ s += x[ks][j]; s2 += x[ks][j]*x[ks][j]; }
            }
            s  += __shfl_xor(s, 16, 64);  s2 += __shfl_xor(s2, 16, 64);
            s  += __shfl_xor(s, 32, 64);  s2 += __shfl_xor(s2, 32, 64);
            float mean = s*(1.f/128.f);
            float var  = s2*(1.f/128.f) - mean*mean;
            float rs = rsqrtf(var + 1e-5f);
            #pragma unroll
            for(int ks=0; ks<4; ++ks){
                float y[8];
                #pragma unroll
                for(int j=0;j<8;++j)
                    y[j] = (x[ks][j]-mean)*rs*bf2f((u16)wf[ks][j]) + bf2f((u16)bfv[ks][j]);
                union{ int4 i; bh8 hh; } ua;
                ua.i.x = (int)((u32)f2bf(y[0]) | ((u32)f2bf(y[1])<<16));
                ua.i.y = (int)((u32)f2bf(y[2]) | ((u32)f2bf(y[3])<<16));
                ua.i.z = (int)((u32)f2bf(y[4]) | ((u32)f2bf(y[5])<<16));
                ua.i.w = (int)((u32)f2bf(y[6]) | ((u32)f2bf(y[7])<<16));
                a[mt][ks] = ua.hh;
            }
            // R6: fence scheduling so mt bodies don't interleave (caps register
            // liveness at ~40 instead of 4x32; R5's spills came from this).
            __builtin_amdgcn_sched_barrier(0);
        }
    }
    bh8 onesf;
    { union{int4 i; bh8 hh;} u2; u2.i.x=u2.i.y=u2.i.z=u2.i.w=0x3F803F80; onesf = u2.hh; }

    __syncthreads();

    f32x4 gacc[4][2];
    // ---- phase 1 (merged): B = [ck0 ck1 | v0 v1 | g0 g1], shared A ----
    {
        f32x4 acc[4][6];
        #pragma unroll
        for(int mt=0;mt<4;++mt)
            #pragma unroll
            for(int j=0;j<6;++j) acc[mt][j] = (f32x4){0,0,0,0};
        #pragma unroll
        for(int ks=0; ks<4; ++ks){
            bh8 b[6];
            b[0] = ld_frag(pb + P_CKW + h*4096 + lm*128            + ks*32 + quad*8);
            b[1] = ld_frag(pb + P_CKW + h*4096 + (16+lm)*128       + ks*32 + quad*8);
            b[2] = ld_frag(pb + P_VW + (size_t)(h*32 + lm)*128     + ks*32 + quad*8);
            b[3] = ld_frag(pb + P_VW + (size_t)(h*32 + 16+lm)*128  + ks*32 + quad*8);
            b[4] = ld_frag(pb + P_GW + (size_t)(h*32 + lm)*128     + ks*32 + quad*8);
            b[5] = ld_frag(pb + P_GW + (size_t)(h*32 + 16+lm)*128  + ks*32 + quad*8);
            #pragma unroll
            for(int mt=0; mt<4; ++mt)
                #pragma unroll
                for(int j=0;j<6;++j)
                    acc[mt][j] = MFMA(a[mt][ks], b[j], acc[mt][j], 0,0,0);
        }
        float bk0 = bf2f(pb[P_CKB + h*32 + lm]);
        float bk1 = bf2f(pb[P_CKB + h*32 + 16 + lm]);
        float bv0 = bf2f(pb[P_VB + h*32 + lm]);
        float bv1 = bf2f(pb[P_VB + h*32 + 16 + lm]);
        float bg0 = bf2f(pb[P_GB + h*32 + lm]);
        float bg1 = bf2f(pb[P_GB + h*32 + 16 + lm]);
        #pragma unroll
        for(int mt=0; mt<4; ++mt){
            int n0 = wv*64 + mt*16 + quad*4;
            float ep0[4], em0[4], ep1[4], em1[4], v0[4], v1[4];
            #pragma unroll
            for(int r=0; r<4; ++r){
                float mk = mask_f[n0+r];
                float m0 = fminf(8.f, fmaxf(-8.f, acc[mt][0][r] + bk0));
                float m1 = fminf(8.f, fmaxf(-8.f, acc[mt][1][r] + bk1));
                ep0[r] = __expf( m0)*mk;  em0[r] = __expf(-m0)*mk;
                ep1[r] = __expf( m1)*mk;  em1[r] = __expf(-m1)*mk;
                v0[r] = (acc[mt][2][r] + bv0)*mk;
                v1[r] = (acc[mt][3][r] + bv1)*mk;
                gacc[mt][0][r] = 1.f/(1.f + __expf(-(acc[mt][4][r] + bg0)));
                gacc[mt][1][r] = 1.f/(1.f + __expf(-(acc[mt][5][r] + bg1)));
            }
            *(int2*)(kfT + (size_t)(lm   )*ST_N + n0) = pk4(ep0[0],ep0[1],ep0[2],ep0[3]);
            *(int2*)(kfT + (size_t)(lm+32)*ST_N + n0) = pk4(em0[0],em0[1],em0[2],em0[3]);
            *(int2*)(kfT + (size_t)(lm+16)*ST_N + n0) = pk4(ep1[0],ep1[1],ep1[2],ep1[3]);
            *(int2*)(kfT + (size_t)(lm+48)*ST_N + n0) = pk4(em1[0],em1[1],em1[2],em1[3]);
            *(int2*)(vT  + (size_t)(lm   )*ST_N + n0) = pk4(v0[0],v0[1],v0[2],v0[3]);
            *(int2*)(vT  + (size_t)(16+lm)*ST_N + n0) = pk4(v1[0],v1[1],v1[2],v1[3]);
        }
    }
    __syncthreads();
    // ---- phase 2: kvT[d][f] = sum_n kfT[f][n]*vT[d][n]; ksum via ones-frag ----
    {
        f32x4 acc0=(f32x4){0,0,0,0}, acc1=(f32x4){0,0,0,0}, acc2=(f32x4){0,0,0,0};
        #pragma unroll
        for(int ks=0; ks<8; ++ks){
            bh8 aa = ld_frag(kfT + (size_t)(wv*16+lm)*ST_N + ks*32 + quad*8);
            bh8 b0 = ld_frag(vT + (size_t)lm*ST_N      + ks*32 + quad*8);
            bh8 b1 = ld_frag(vT + (size_t)(16+lm)*ST_N + ks*32 + quad*8);
            acc0 = MFMA(aa, b0, acc0, 0,0,0);
            acc1 = MFMA(aa, b1, acc1, 0,0,0);
            acc2 = MFMA(aa, onesf, acc2, 0,0,0);
        }
        int f0 = wv*16 + quad*4;
        *(int2*)(kvT + (size_t)(lm   )*ST_F + f0) = pk4(acc0[0],acc0[1],acc0[2],acc0[3]);
        *(int2*)(kvT + (size_t)(16+lm)*ST_F + f0) = pk4(acc1[0],acc1[1],acc1[2],acc1[3]);
        if(lm==0)
            *(int2*)(kvT + (size_t)32*ST_F + f0) = pk4(acc2[0],acc2[1],acc2[2],acc2[3]);
    }
    __syncthreads();
    // ---- phase 3: qf[n][f] = featmap(zn·Wc_q^T + bc_q)  (aliases kfT/vT) ----
    {
        f32x4 acc[4][2];
        #pragma unroll
        for(int mt=0;mt<4;++mt){ acc[mt][0]=(f32x4){0,0,0,0}; acc[mt][1]=(f32x4){0,0,0,0}; }
        #pragma unroll
        for(int ks=0; ks<4; ++ks){
            bh8 b0 = ld_frag(pb + P_CQW + h*4096 + lm*128      + ks*32 + quad*8);
            bh8 b1 = ld_frag(pb + P_CQW + h*4096 + (16+lm)*128 + ks*32 + quad*8);
            #pragma unroll
            for(int mt=0; mt<4; ++mt){
                acc[mt][0] = MFMA(a[mt][ks], b0, acc[mt][0], 0,0,0);
                acc[mt][1] = MFMA(a[mt][ks], b1, acc[mt][1], 0,0,0);
            }
        }
        float bb0 = bf2f(pb[P_CQB + h*32 + lm]);
        float bb1 = bf2f(pb[P_CQB + h*32 + 16 + lm]);
        #pragma unroll
        for(int mt=0; mt<4; ++mt)
            #pragma unroll
            for(int r=0; r<4; ++r){
                int n = wv*64 + mt*16 + quad*4 + r;
                float m0 = fminf(8.f, fmaxf(-8.f, acc[mt][0][r] + bb0));
                float m1 = fminf(8.f, fmaxf(-8.f, acc[mt][1][r] + bb1));
                qf[n*ST_F + lm     ] = f2bf(__expf( m0));
                qf[n*ST_F + lm + 32] = f2bf(__expf(-m0));
                qf[n*ST_F + lm + 16] = f2bf(__expf( m1));
                qf[n*ST_F + lm + 48] = f2bf(__expf(-m1));
            }
    }
    __syncthreads();
    // ---- phase 4: out = (qf·kvT^T)/den * gate ----
    {
        f32x4 acc[4][3];
        #pragma unroll
        for(int mt=0;mt<4;++mt)
            #pragma unroll
            for(int nt=0;nt<3;++nt) acc[mt][nt]=(f32x4){0,0,0,0};
        #pragma unroll
        for(int ks=0; ks<2; ++ks){
            bh8 b0 = ld_frag(kvT + (size_t)lm*ST_F      + ks*32 + quad*8);
            bh8 b1 = ld_frag(kvT + (size_t)(16+lm)*ST_F + ks*32 + quad*8);
            bh8 b2 = ld_frag(kvT + (size_t)32*ST_F      + ks*32 + quad*8); // ksum, broadcast
            #pragma unroll
            for(int mt=0; mt<4; ++mt){
                bh8 aa = ld_frag(qf + (size_t)(wv*64+mt*16+lm)*ST_F + ks*32 + quad*8);
                acc[mt][0] = MFMA(aa, b0, acc[mt][0], 0,0,0);
                acc[mt][1] = MFMA(aa, b1, acc[mt][1], 0,0,0);
                acc[mt][2] = MFMA(aa, b2, acc[mt][2], 0,0,0);
            }
        }
        #pragma unroll
        for(int mt=0; mt<4; ++mt)
            #pragma unroll
            for(int r=0; r<4; ++r){
                int n = wv*64 + mt*16 + quad*4 + r;
                float rcp = 1.f / fmaxf(acc[mt][2][r], 1e-6f);
                u16* op = attn + ((size_t)row*256 + n)*128 + h*32;
                op[lm]    = f2bf(acc[mt][0][r]*rcp*gacc[mt][0][r]);
                op[16+lm] = f2bf(acc[mt][1][r]*rcp*gacc[mt][1][r]);
            }
    }
}

// ---------------- MFMA o-proj: attn(bf16) -> out(f32), x mask ----------------
#define LDS_P 136
__global__ __launch_bounds__(256,2)
void oproj_kernel(const u16* __restrict__ attn, const u16* __restrict__ pb,
                  const int* __restrict__ mask, float* __restrict__ out){
    __shared__ u16 st[128*LDS_P];
    int tid = threadIdx.x;
    int lane = tid&63, wv = tid>>6;
    int mhalf = (wv>>1)*64, nhalf = (wv&1)*64;
    int lm = lane&15, quad = lane>>4;
    int m0 = blockIdx.x*128;

    f32x4 acc[4][4];
    #pragma unroll
    for(int mt=0;mt<4;++mt)
        #pragma unroll
        for(int nt=0;nt<4;++nt)
            acc[mt][nt] = (f32x4){0.f,0.f,0.f,0.f};

    const u16* Abase = attn + (size_t)(m0 + mhalf + lm)*128 + quad*8;
    const u16* W = pb + P_OW;
    #pragma unroll
    for(int ks=0; ks<4; ++ks){
        bh8 a[4], b[4];
        #pragma unroll
        for(int mt=0; mt<4; ++mt)
            a[mt] = ld_frag(Abase + (size_t)mt*16*128 + ks*32);
        #pragma unroll
        for(int nt=0; nt<4; ++nt)
            b[nt] = ld_frag(W + (size_t)(nhalf + nt*16 + lm)*128 + ks*32 + quad*8);
        #pragma unroll
        for(int mt=0; mt<4; ++mt)
            #pragma unroll
            for(int nt=0; nt<4; ++nt)
                acc[mt][nt] = MFMA(a[mt], b[nt], acc[mt][nt], 0, 0, 0);
    }
    float bv[4];
    #pragma unroll
    for(int nt=0; nt<4; ++nt) bv[nt] = bf2f(pb[P_OB + nhalf + nt*16 + lm]);
    #pragma unroll
    for(int mt=0; mt<4; ++mt){
        int mrow = m0 + mhalf + mt*16 + quad*4;
        float mk[4];
        #pragma unroll
        for(int r=0;r<4;++r) mk[r] = (float)mask[mrow+r];
        #pragma unroll
        for(int nt=0; nt<4; ++nt)
            #pragma unroll
            for(int r=0; r<4; ++r){
                float x = (acc[mt][nt][r] + bv[nt]) * mk[r];
                st[(mhalf + mt*16 + quad*4 + r)*LDS_P + nhalf + nt*16 + lm] = f2bf(x);
            }
    }
    __syncthreads();
    {
        int row = tid>>1, half = tid&1;
        const u16* src = st + row*LDS_P + half*64;
        float* dst = out + (size_t)(m0 + row)*128 + half*64;
        #pragma unroll
        for(int it=0; it<8; ++it){
            float f[8]; cvt8(((const int4*)src)[it], f);
            float4 lo; lo.x=f[0]; lo.y=f[1]; lo.z=f[2]; lo.w=f[3];
            float4 hi; hi.x=f[4]; hi.y=f[5]; hi.z=f[6]; hi.w=f[7];
            ((float4*)dst)[it*2  ] = lo;
            ((float4*)dst)[it*2+1] = hi;
        }
    }
}

// ---------------- launch: 3 kernels (ln fused into mega) ----------------
extern "C" void kernel_launch(void* const* d_in, const int* in_sizes, int n_in,
                              void* d_out, int out_size, void* d_ws, size_t ws_size,
                              hipStream_t stream){
    const float* z    = (const float*)d_in[0];
    const int*   mask = (const int*)d_in[1];

    char* ws = (char*)d_ws;
    const size_t MB = (size_t)1<<20;
    u16* attn = (u16*)(ws + 16*MB);     // 16 MB [t][128] bf16
    u16* pb   = (u16*)(ws + 32*MB);     // ~231 KB bf16 param block (incl. combined weights)

    prep_params<<<NCONV+129,256,0,stream>>>(
        (const float*)d_in[2],  (const float*)d_in[3],  (const float*)d_in[4],  (const float*)d_in[5],
        (const float*)d_in[6],  (const float*)d_in[7],  (const float*)d_in[8],  (const float*)d_in[9],
        (const float*)d_in[10], (const float*)d_in[11], (const float*)d_in[12], (const float*)d_in[13],
        (const float*)d_in[14], (const float*)d_in[15], (const float*)d_in[16], (const float*)d_in[17],
        pb);
    mega_kernel<<<1024,256,0,stream>>>(z, mask, pb, attn);
    oproj_kernel<<<512,256,0,stream>>>(attn, pb, mask, (float*)d_out);
}